// Round 4
// baseline (631.201 us; speedup 1.0000x reference)
//
#include <hip/hip_runtime.h>
#include <cstdint>
#include <cstddef>

// Problem shape (fixed by the reference): B=8, C=192, Tx=512, Ty=2048.
#define BB 8
#define CC 192
#define TXX 512
#define TYY 2048
#define NG_MAX (TYY / 8)   // 256 groups of 8 rows

#define NEG_INF (-1e9f)
#define HALF_LOG_2PI 0.9189385332046727f  // 0.5*log(2*pi)

// ---- output layout (floats, concatenated in return order) ----
#define O1 8388608
#define O2 11534336
#define O3 14680064
#define O4 14680065

// ---- workspace layout (bytes) ----
#define WS_NEG   0           // neg_cent fp32 [B,Ty,Tx]           33,554,432 B
#define WS_S     33554432    // s_p_sq_r [B,C,Tx]                  3,145,728 B
#define WS_MSR   36700160    // m_p * s  [B,C,Tx]                  3,145,728 B
#define WS_BIAS  39845888    // nc1+nc4  [B,Tx]                       16,384 B
#define WS_DIRS  39862272    // dir bits [B,Ty/4,64] dwords        1,048,576 B
#define WS_IDX   40910848    // idx_map  [B,Ty] int                   65,536 B
#define WS_LENS  40976384    // int text_len[8], spec_len[8]             64 B
#define WS_PART  40976448    // kl partials [3072] float              12,288 B

typedef float f32x4 __attribute__((ext_vector_type(4)));

// ---------------------------------------------------------------------------
__global__ void k_zero(float* __restrict__ out) {
    int64_t i = (int64_t)blockIdx.x * blockDim.x + threadIdx.x;
    const int64_t n4 = (int64_t)BB * TYY * TXX / 4;
    float4 z4 = make_float4(0.f, 0.f, 0.f, 0.f);
    float4* p4 = (float4*)out;
    for (int64_t k = i; k < n4; k += (int64_t)gridDim.x * blockDim.x) p4[k] = z4;
    if (i < BB * TXX) out[O4 + i] = 0.0f;
}

__global__ void k_prep(const float* __restrict__ logs_p, const float* __restrict__ m_p,
                       float* __restrict__ s, float* __restrict__ msr) {
    int i = blockIdx.x * blockDim.x + threadIdx.x;
    float lp = logs_p[i], m = m_p[i];
    float sv = expf(-2.0f * lp);
    s[i] = sv;
    msr[i] = m * sv;
}

__global__ void k_bias(const float* __restrict__ logs_p, const float* __restrict__ m_p,
                       const float* __restrict__ msr, float* __restrict__ bias) {
    int i = blockIdx.x * blockDim.x + threadIdx.x;  // B*Tx = 4096 threads
    int b = i >> 9, x = i & (TXX - 1);
    size_t base = (size_t)b * CC * TXX + x;
    const float* lpb = logs_p + base;
    const float* mb  = m_p + base;
    const float* msb = msr + base;
    float acc = 0.f;
#pragma unroll 8
    for (int c = 0; c < CC; ++c)
        acc += -HALF_LOG_2PI - lpb[(size_t)c * TXX] - 0.5f * mb[(size_t)c * TXX] * msb[(size_t)c * TXX];
    bias[i] = acc;
}

__global__ void k_len(const float* __restrict__ tmask, const float* __restrict__ smask,
                      int* __restrict__ lens) {
    __shared__ float red[256];
    int b = blockIdx.x, tid = threadIdx.x;
    float ts = 0.f;
    for (int i = tid; i < TXX; i += 256) ts += tmask[b * TXX + i];
    red[tid] = ts; __syncthreads();
    for (int s = 128; s > 0; s >>= 1) { if (tid < s) red[tid] += red[tid + s]; __syncthreads(); }
    if (tid == 0) lens[b] = (int)(red[0] + 0.5f);
    __syncthreads();
    float ss = 0.f;
    for (int i = tid; i < TYY; i += 256) ss += smask[b * TYY + i];
    red[tid] = ss; __syncthreads();
    for (int s = 128; s > 0; s >>= 1) { if (tid < s) red[tid] += red[tid + s]; __syncthreads(); }
    if (tid == 0) lens[8 + b] = (int)(red[0] + 0.5f);
}

// neg_cent GEMM (R11 v1 tile: 64x64, BK=16, 8 blocks/CU).
// Masked tiles exit early (block-uniform). Poison in masked region is
// harmless to the DP/backtrack (see R14 note).
__global__ __launch_bounds__(256) void k_gemm(const float* __restrict__ z,
                                              const float* __restrict__ msr,
                                              const float* __restrict__ sarr,
                                              const float* __restrict__ bias,
                                              const int* __restrict__ lens,
                                              float* __restrict__ neg) {
    int x0 = blockIdx.x * 64, t0 = blockIdx.y * 64, b = blockIdx.z;
    if (x0 >= lens[b] || t0 >= lens[8 + b]) return;   // masked tile

    __shared__ float Zs[16][68], Ms[16][68], Ss[16][68];  // +4 pad
    int tid = threadIdx.x;
    int tx = tid & 15, ty = tid >> 4;
    const float* zb = z    + (size_t)b * CC * TYY;
    const float* mb = msr  + (size_t)b * CC * TXX;
    const float* sb = sarr + (size_t)b * CC * TXX;
    int lr = tid >> 4, lc = (tid & 15) * 4;
    float acc[4][4] = {};
    for (int k0 = 0; k0 < CC; k0 += 16) {
        float4 zv = *(const float4*)(zb + (size_t)(k0 + lr) * TYY + t0 + lc);
        float4 mv = *(const float4*)(mb + (size_t)(k0 + lr) * TXX + x0 + lc);
        float4 sv = *(const float4*)(sb + (size_t)(k0 + lr) * TXX + x0 + lc);
        __syncthreads();
        *(float4*)&Zs[lr][lc] = zv;
        *(float4*)&Ms[lr][lc] = mv;
        *(float4*)&Ss[lr][lc] = sv;
        __syncthreads();
#pragma unroll
        for (int k = 0; k < 16; ++k) {
            float4 a4  = *(const float4*)&Zs[k][ty * 4];
            float4 bm4 = *(const float4*)&Ms[k][tx * 4];
            float4 bs4 = *(const float4*)&Ss[k][tx * 4];
            float av[4]  = {a4.x, a4.y, a4.z, a4.w};
            float bmv[4] = {bm4.x, bm4.y, bm4.z, bm4.w};
            float bsv[4] = {bs4.x, bs4.y, bs4.z, bs4.w};
#pragma unroll
            for (int i2 = 0; i2 < 4; ++i2) {
                float a2 = -0.5f * av[i2] * av[i2];
#pragma unroll
                for (int j = 0; j < 4; ++j)
                    acc[i2][j] += av[i2] * bmv[j] + a2 * bsv[j];
            }
        }
    }
    float4 b4 = *(const float4*)(bias + b * TXX + x0 + tx * 4);
    float bv[4] = {b4.x, b4.y, b4.z, b4.w};
#pragma unroll
    for (int i2 = 0; i2 < 4; ++i2) {
        int t = t0 + ty * 4 + i2;
        float4 o;
        o.x = acc[i2][0] + bv[0]; o.y = acc[i2][1] + bv[1];
        o.z = acc[i2][2] + bv[2]; o.w = acc[i2][3] + bv[3];
        *(float4*)(neg + ((size_t)b * TYY + t) * TXX + x0 + tx * 4) = o;
    }
}

// ---------------------------------------------------------------------------
// MAS forward pass v7 (R18): one wave per batch, LDS-ring prefetch via
// global_load_lds (zero VGPR cost -> regalloc cannot collapse the pipeline).
//
// R16/R17 post-mortem: v5/v6 prefetched into VGPR buffers via asm loads.
// VGPR_Count=116 proved the allocator reused/serialized the asm outputs
// (3 resident buffers need >=192 VGPRs), injecting its own waits -> only
// 203 us. v6's bundled asm micro-opts crashed. v7 removes the fragile
// mechanism entirely:
//   - STAGE(g): 16x global_load_lds (16B/lane) into a 4-slot x 16KB LDS
//     ring. Destinations are LDS: no registers, no regalloc interference.
//   - counted vmcnt (16 loads + 2 dir-stores per group): steady wait
//     vmcnt(48) drains exactly the consumed group + stale stores; tails
//     32/16/0. sched_barrier(0) after each wait (rule #18). No barriers
//     (single wave issues and consumes).
//   - slot-reuse race-free: iter-g ds_reads complete (lgkm drained before
//     v-use) before iter-(g+1)'s STAGE even issues.
//   - LDS bank swizzle P = L ^ (((L>>7)&1)<<4) (involution, verified both
//     directions): realized as pre-swizzled GLOBAL source (linear LDS dest,
//     rule #21) + swizzled read offsets sw0/sw1. Read pattern becomes
//     2-way (free) instead of 4-way conflicted.
//   - DP row body identical to v5 (proven); x==y fold via lane==g.
// Dirs layout identical (k_bwd unchanged).
// ---------------------------------------------------------------------------
#define WAIT_VM(N) do {                                                   \
    asm volatile("s_waitcnt vmcnt(" #N ")" ::: "memory");                 \
    __builtin_amdgcn_sched_barrier(0);                                    \
} while (0)

#define GLDS(GP, LP)                                                      \
    __builtin_amdgcn_global_load_lds(                                     \
        (__attribute__((address_space(1))) void*)(GP),                    \
        (__attribute__((address_space(3))) void*)(LP), 16, 0, 0)

// Stage group G (8 rows x 512 f = 16KB) into ring slot G&3.
// gsrc is per-lane (includes the swizzled lane*16 offset); LDS base is
// wave-uniform (HW adds lane*16).
#define STAGE(G) do {                                                     \
    const char* gb_ = gsrc + (size_t)(G) * 16384;                         \
    char* lb_ = ring + (((G) & 3) * 16384);                               \
    _Pragma("unroll")                                                     \
    for (int c_ = 0; c_ < 16; ++c_)                                       \
        GLDS(gb_ + c_ * 1024, lb_ + c_ * 1024);                           \
} while (0)

#define DPROW(SL, YB, R) do {                                                 \
    int y_ = (YB) + (R);                                                      \
    const char* rp_ = (SL) + (R) * 2048 + lbase;                              \
    f32x4 lo_ = *(const f32x4*)(rp_ + sw0);                                   \
    f32x4 hi_ = *(const f32x4*)(rp_ + sw1);                                   \
    float s0_ = lo_[0], s1_ = lo_[1], s2_ = lo_[2], s3_ = lo_[3];             \
    float s4_ = hi_[0], s5_ = hi_[1], s6_ = hi_[2], s7_ = hi_[3];             \
    unsigned d_ = 0;                                                          \
    if (y_ == 0) {                                                            \
        if (lane == 0) v[0] = s0_;   /* only x==0 scored on row 0 */          \
    } else {                                                                  \
        float pl_ = __int_as_float(__builtin_amdgcn_update_dpp(               \
            0, __float_as_int(v[7]), 0x138, 0xF, 0xF, false));                \
        if (lane == 0) pl_ = NEG_INF;                                         \
        float n0_ = s0_ + fmaxf(v[0], pl_);  if (pl_  > v[0]) d_ |= 1u;       \
        float n1_ = s1_ + fmaxf(v[1], v[0]); if (v[0] > v[1]) d_ |= 2u;       \
        float n2_ = s2_ + fmaxf(v[2], v[1]); if (v[1] > v[2]) d_ |= 4u;       \
        float n3_ = s3_ + fmaxf(v[3], v[2]); if (v[2] > v[3]) d_ |= 8u;       \
        float n4_ = s4_ + fmaxf(v[4], v[3]); if (v[3] > v[4]) d_ |= 16u;      \
        float n5_ = s5_ + fmaxf(v[5], v[4]); if (v[4] > v[5]) d_ |= 32u;      \
        float n6_ = s6_ + fmaxf(v[6], v[5]); if (v[5] > v[6]) d_ |= 64u;      \
        float n7_ = s7_ + fmaxf(v[7], v[6]); if (v[6] > v[7]) d_ |= 128u;     \
        v[0] = n0_; v[1] = n1_; v[2] = n2_; v[3] = n3_;                       \
        v[4] = n4_; v[5] = n5_; v[6] = n6_; v[7] = n7_;                       \
    }                                                                         \
    d_ |= fold_ << (R);                      /* fold x==y (lane==g) */        \
    acc |= d_ << (((R) & 3) * 8);                                             \
    if (((R) & 3) == 3) { db32[(y_ >> 2) * 64 + lane] = acc; acc = 0; }       \
} while (0)

__global__ __launch_bounds__(64, 1) void k_fwd(const float* __restrict__ neg,
                                               const int* __restrict__ lens,
                                               uint32_t* __restrict__ dirs) {
    __shared__ __align__(16) char ring[4 * 16384];   // 64 KiB ring
    int b = blockIdx.x, lane = threadIdx.x;
    // global source pre-swizzle: lane fetches granule lane ^ ((lane>>3)&1)
    unsigned gsw = ((unsigned)lane * 16u) ^ ((((unsigned)lane >> 3) & 1u) << 4);
    const char* gsrc = (const char*)(neg + (size_t)b * TYY * TXX) + gsw;
    unsigned lbase = (unsigned)lane * 32u;
    unsigned sw0 = (((unsigned)lane >> 2) & 1u) << 4;   // swizzled lo offset
    unsigned sw1 = sw0 ^ 16u;                           // swizzled hi offset
    uint32_t* db32 = dirs + (size_t)b * (TYY / 4) * 64;
    int slen = lens[8 + b];
    int ng = (slen + 7) >> 3;    // 192..256 (slen >= 1536)

    float v[8];
#pragma unroll
    for (int j = 0; j < 8; ++j) v[j] = NEG_INF;
    unsigned acc = 0;

    STAGE(0); STAGE(1); STAGE(2);   // 3-group lead (~48 vmem in flight)

    for (int g = 0; g < ng; ++g) {
        if (g + 3 < ng)      { STAGE(g + 3); WAIT_VM(48); }
        else if (g + 2 < ng) { WAIT_VM(32); }
        else if (g + 1 < ng) { WAIT_VM(16); }
        else                 { WAIT_VM(0);  }
        const char* sl = ring + ((g & 3) * 16384);
        unsigned fold_ = (lane == g) ? 1u : 0u;
        int yb = 8 * g;
        DPROW(sl, yb, 0); DPROW(sl, yb, 1); DPROW(sl, yb, 2); DPROW(sl, yb, 3);
        DPROW(sl, yb, 4); DPROW(sl, yb, 5); DPROW(sl, yb, 6); DPROW(sl, yb, 7);
    }
}

// MAS backtrack: 32-row slabs; lane j holds a 64-bit window of row y0-j's
// bits; move = (idx!=0) & bit (x==y folded in fwd).
__global__ __launch_bounds__(64, 1) void k_bwd(const int* __restrict__ lens,
                                               const uint32_t* __restrict__ dirs,
                                               int* __restrict__ idx_map) {
    int b = blockIdx.x, lane = threadIdx.x;
    const uint32_t* db32 = dirs + (size_t)b * (TYY / 4) * 64;
    int tlen = lens[b], slen = lens[8 + b];

    int idx = tlen - 1;
    int y0 = slen - 1;
    while (y0 >= 0) {
        int nsteps = (y0 + 1 < 32) ? y0 + 1 : 32;
        int y = y0 - lane;
        int yy = (y < 0) ? 0 : y;
        int w0 = (idx >> 5) - 1;
        if (w0 < 0) w0 = 0;
        if (w0 > 14) w0 = 14;
        int qrow = (yy >> 2) * 64;
        int byteoff = (yy & 3) * 8;
        uint32_t lo = 0, hi = 0;
        if (lane < 32) {
#pragma unroll
            for (int k = 0; k < 4; ++k)
                lo |= ((db32[qrow + 4 * w0 + k] >> byteoff) & 0xffu) << (8 * k);
#pragma unroll
            for (int k = 0; k < 4; ++k)
                hi |= ((db32[qrow + 4 * w0 + 4 + k] >> byteoff) & 0xffu) << (8 * k);
        }
        int base = w0 << 5;
        int cap = 0;
#pragma unroll
        for (int j = 0; j < 32; ++j) {
            if (lane == j) cap = idx;
            uint32_t l = (uint32_t)__builtin_amdgcn_readlane((int)lo, j);
            uint32_t h = (uint32_t)__builtin_amdgcn_readlane((int)hi, j);
            int bp = idx - base;              // 0..63
            uint32_t word = (bp & 32) ? h : l;
            int bit = (int)((word >> (bp & 31)) & 1u);
            int move = (int)(idx != 0) & bit;
            idx -= move;
        }
        if (lane < nsteps) idx_map[b * TYY + (y0 - lane)] = cap;
        y0 -= 32;
    }
}

// Scatter path one-hots + duration histogram from idx_map.
__global__ void k_scatter(const int* __restrict__ lens, const int* __restrict__ idx_map,
                          float* __restrict__ out) {
    int i = blockIdx.x * blockDim.x + threadIdx.x;  // B*Ty threads
    int b = i >> 11, y = i & (TYY - 1);
    if (y < lens[8 + b]) {
        int x = idx_map[i];
        out[(size_t)i * TXX + x] = 1.0f;
        atomicAdd(&out[O4 + b * TXX + x], 1.0f);
    }
}

// Gather m_p/logs_p onto spec frames via idx_map; fused KL partial sums.
__global__ __launch_bounds__(256) void k_gather(const float* __restrict__ z_p,
                                                const float* __restrict__ m_p,
                                                const float* __restrict__ logs_p,
                                                const float* __restrict__ logs_q,
                                                const int* __restrict__ lens,
                                                const int* __restrict__ idx_map,
                                                float* __restrict__ out,
                                                float* __restrict__ partials) {
    const int S = BB * CC * TYY / 4;
    int base = blockIdx.x * 256 + threadIdx.x;
    float klsum = 0.f;
#pragma unroll
    for (int r = 0; r < 4; ++r) {
        int i = base + r * S;
        int t = i & (TYY - 1);
        int bc = i >> 11;
        int b = bc / CC;
        float ma = 0.f, la = 0.f;
        if (t < lens[8 + b]) {
            int x = idx_map[b * TYY + t];
            size_t off = (size_t)bc * TXX + x;
            ma = m_p[off];
            la = logs_p[off];
            float zv = z_p[i], lq = logs_q[i];
            float dz = zv - ma;
            klsum += la - lq - 0.5f + 0.5f * dz * dz * expf(-2.0f * la);
        }
        out[O1 + i] = ma;
        out[O2 + i] = la;
    }
    for (int o = 32; o > 0; o >>= 1) klsum += __shfl_down(klsum, o);
    __shared__ float red[4];
    if ((threadIdx.x & 63) == 0) red[threadIdx.x >> 6] = klsum;
    __syncthreads();
    if (threadIdx.x == 0) partials[blockIdx.x] = red[0] + red[1] + red[2] + red[3];
}

__global__ void k_final(const float* __restrict__ partials, const int* __restrict__ lens,
                        float* __restrict__ out) {
    float s = 0.f;
    for (int i = threadIdx.x; i < 3072; i += 256) s += partials[i];
    for (int o = 32; o > 0; o >>= 1) s += __shfl_down(s, o);
    __shared__ float red[4];
    if ((threadIdx.x & 63) == 0) red[threadIdx.x >> 6] = s;
    __syncthreads();
    if (threadIdx.x == 0) {
        float tot = 0.f;
        for (int b = 0; b < 8; ++b) tot += (float)lens[8 + b];
        out[O3] = (red[0] + red[1] + red[2] + red[3]) / tot;
    }
}

extern "C" void kernel_launch(void* const* d_in, const int* in_sizes, int n_in,
                              void* d_out, int out_size, void* d_ws, size_t ws_size,
                              hipStream_t stream) {
    const float* z_p    = (const float*)d_in[0];
    const float* m_p    = (const float*)d_in[1];
    const float* logs_p = (const float*)d_in[2];
    const float* logs_q = (const float*)d_in[3];
    const float* tmask  = (const float*)d_in[4];
    const float* smask  = (const float*)d_in[5];
    float* out = (float*)d_out;
    char* ws = (char*)d_ws;

    float*    neg      = (float*)(ws + WS_NEG);
    float*    sarr     = (float*)(ws + WS_S);
    float*    msr      = (float*)(ws + WS_MSR);
    float*    bias     = (float*)(ws + WS_BIAS);
    uint32_t* dirs     = (uint32_t*)(ws + WS_DIRS);
    int*      idx_map  = (int*)(ws + WS_IDX);
    int*      lens     = (int*)(ws + WS_LENS);
    float*    partials = (float*)(ws + WS_PART);

    hipLaunchKernelGGL(k_zero,    dim3(2048),      dim3(256), 0, stream, out);
    hipLaunchKernelGGL(k_prep,    dim3(3072),      dim3(256), 0, stream, logs_p, m_p, sarr, msr);
    hipLaunchKernelGGL(k_bias,    dim3(16),        dim3(256), 0, stream, logs_p, m_p, msr, bias);
    hipLaunchKernelGGL(k_len,     dim3(8),         dim3(256), 0, stream, tmask, smask, lens);
    hipLaunchKernelGGL(k_gemm,    dim3(8, 32, 8),  dim3(256), 0, stream, z_p, msr, sarr, bias, lens, neg);
    hipLaunchKernelGGL(k_fwd,     dim3(8),         dim3(64),  0, stream, neg, lens, dirs);
    hipLaunchKernelGGL(k_bwd,     dim3(8),         dim3(64),  0, stream, lens, dirs, idx_map);
    hipLaunchKernelGGL(k_scatter, dim3(64),        dim3(256), 0, stream, lens, idx_map, out);
    hipLaunchKernelGGL(k_gather,  dim3(3072),      dim3(256), 0, stream, z_p, m_p, logs_p, logs_q,
                       lens, idx_map, out, partials);
    hipLaunchKernelGGL(k_final,   dim3(1),         dim3(256), 0, stream, partials, lens, out);
}

// Round 5
// 591.229 us; speedup vs baseline: 1.0676x; 1.0676x over previous
//
#include <hip/hip_runtime.h>
#include <cstdint>
#include <cstddef>

// Problem shape (fixed by the reference): B=8, C=192, Tx=512, Ty=2048.
#define BB 8
#define CC 192
#define TXX 512
#define TYY 2048
#define NG_MAX (TYY / 8)   // 256 groups of 8 rows

#define NEG_INF (-1e9f)
#define HALF_LOG_2PI 0.9189385332046727f  // 0.5*log(2*pi)

// ---- output layout (floats, concatenated in return order) ----
#define O1 8388608
#define O2 11534336
#define O3 14680064
#define O4 14680065

// ---- workspace layout (bytes) ----
#define WS_NEG   0           // neg_cent fp32 [B,Ty,Tx]           33,554,432 B
#define WS_S     33554432    // s_p_sq_r [B,C,Tx]                  3,145,728 B
#define WS_MSR   36700160    // m_p * s  [B,C,Tx]                  3,145,728 B
#define WS_BIAS  39845888    // nc1+nc4  [B,Tx]                       16,384 B
#define WS_DIRS  39862272    // dir bits [B,Ty/4,64] dwords        1,048,576 B
#define WS_IDX   40910848    // idx_map  [B,Ty] int                   65,536 B
#define WS_LENS  40976384    // int text_len[8], spec_len[8]             64 B
#define WS_PART  40976448    // kl partials [3072] float              12,288 B

typedef float f32x4 __attribute__((ext_vector_type(4)));

// ---------------------------------------------------------------------------
__global__ void k_zero(float* __restrict__ out) {
    int64_t i = (int64_t)blockIdx.x * blockDim.x + threadIdx.x;
    const int64_t n4 = (int64_t)BB * TYY * TXX / 4;
    float4 z4 = make_float4(0.f, 0.f, 0.f, 0.f);
    float4* p4 = (float4*)out;
    for (int64_t k = i; k < n4; k += (int64_t)gridDim.x * blockDim.x) p4[k] = z4;
    if (i < BB * TXX) out[O4 + i] = 0.0f;
}

__global__ void k_prep(const float* __restrict__ logs_p, const float* __restrict__ m_p,
                       float* __restrict__ s, float* __restrict__ msr) {
    int i = blockIdx.x * blockDim.x + threadIdx.x;
    float lp = logs_p[i], m = m_p[i];
    float sv = expf(-2.0f * lp);
    s[i] = sv;
    msr[i] = m * sv;
}

__global__ void k_bias(const float* __restrict__ logs_p, const float* __restrict__ m_p,
                       const float* __restrict__ msr, float* __restrict__ bias) {
    int i = blockIdx.x * blockDim.x + threadIdx.x;  // B*Tx = 4096 threads
    int b = i >> 9, x = i & (TXX - 1);
    size_t base = (size_t)b * CC * TXX + x;
    const float* lpb = logs_p + base;
    const float* mb  = m_p + base;
    const float* msb = msr + base;
    float acc = 0.f;
#pragma unroll 8
    for (int c = 0; c < CC; ++c)
        acc += -HALF_LOG_2PI - lpb[(size_t)c * TXX] - 0.5f * mb[(size_t)c * TXX] * msb[(size_t)c * TXX];
    bias[i] = acc;
}

__global__ void k_len(const float* __restrict__ tmask, const float* __restrict__ smask,
                      int* __restrict__ lens) {
    __shared__ float red[256];
    int b = blockIdx.x, tid = threadIdx.x;
    float ts = 0.f;
    for (int i = tid; i < TXX; i += 256) ts += tmask[b * TXX + i];
    red[tid] = ts; __syncthreads();
    for (int s = 128; s > 0; s >>= 1) { if (tid < s) red[tid] += red[tid + s]; __syncthreads(); }
    if (tid == 0) lens[b] = (int)(red[0] + 0.5f);
    __syncthreads();
    float ss = 0.f;
    for (int i = tid; i < TYY; i += 256) ss += smask[b * TYY + i];
    red[tid] = ss; __syncthreads();
    for (int s = 128; s > 0; s >>= 1) { if (tid < s) red[tid] += red[tid + s]; __syncthreads(); }
    if (tid == 0) lens[8 + b] = (int)(red[0] + 0.5f);
}

// neg_cent GEMM (R11 v1 tile: 64x64, BK=16, 8 blocks/CU).
// Masked tiles exit early (block-uniform). Poison in masked region is
// harmless to the DP/backtrack (see R14 note).
__global__ __launch_bounds__(256) void k_gemm(const float* __restrict__ z,
                                              const float* __restrict__ msr,
                                              const float* __restrict__ sarr,
                                              const float* __restrict__ bias,
                                              const int* __restrict__ lens,
                                              float* __restrict__ neg) {
    int x0 = blockIdx.x * 64, t0 = blockIdx.y * 64, b = blockIdx.z;
    if (x0 >= lens[b] || t0 >= lens[8 + b]) return;   // masked tile

    __shared__ float Zs[16][68], Ms[16][68], Ss[16][68];  // +4 pad
    int tid = threadIdx.x;
    int tx = tid & 15, ty = tid >> 4;
    const float* zb = z    + (size_t)b * CC * TYY;
    const float* mb = msr  + (size_t)b * CC * TXX;
    const float* sb = sarr + (size_t)b * CC * TXX;
    int lr = tid >> 4, lc = (tid & 15) * 4;
    float acc[4][4] = {};
    for (int k0 = 0; k0 < CC; k0 += 16) {
        float4 zv = *(const float4*)(zb + (size_t)(k0 + lr) * TYY + t0 + lc);
        float4 mv = *(const float4*)(mb + (size_t)(k0 + lr) * TXX + x0 + lc);
        float4 sv = *(const float4*)(sb + (size_t)(k0 + lr) * TXX + x0 + lc);
        __syncthreads();
        *(float4*)&Zs[lr][lc] = zv;
        *(float4*)&Ms[lr][lc] = mv;
        *(float4*)&Ss[lr][lc] = sv;
        __syncthreads();
#pragma unroll
        for (int k = 0; k < 16; ++k) {
            float4 a4  = *(const float4*)&Zs[k][ty * 4];
            float4 bm4 = *(const float4*)&Ms[k][tx * 4];
            float4 bs4 = *(const float4*)&Ss[k][tx * 4];
            float av[4]  = {a4.x, a4.y, a4.z, a4.w};
            float bmv[4] = {bm4.x, bm4.y, bm4.z, bm4.w};
            float bsv[4] = {bs4.x, bs4.y, bs4.z, bs4.w};
#pragma unroll
            for (int i2 = 0; i2 < 4; ++i2) {
                float a2 = -0.5f * av[i2] * av[i2];
#pragma unroll
                for (int j = 0; j < 4; ++j)
                    acc[i2][j] += av[i2] * bmv[j] + a2 * bsv[j];
            }
        }
    }
    float4 b4 = *(const float4*)(bias + b * TXX + x0 + tx * 4);
    float bv[4] = {b4.x, b4.y, b4.z, b4.w};
#pragma unroll
    for (int i2 = 0; i2 < 4; ++i2) {
        int t = t0 + ty * 4 + i2;
        float4 o;
        o.x = acc[i2][0] + bv[0]; o.y = acc[i2][1] + bv[1];
        o.z = acc[i2][2] + bv[2]; o.w = acc[i2][3] + bv[3];
        *(float4*)(neg + ((size_t)b * TYY + t) * TXX + x0 + tx * 4) = o;
    }
}

// ---------------------------------------------------------------------------
// MAS forward pass v8 (R19): v7's LDS-ring staging (proven correct, zero
// regalloc interference) + GROUP-level LDS->reg loads.
//
// R18 post-mortem: v7 = 253 us = 296 cy/row. Staging was clean but each
// DPROW issued its own 2 ds_read_b128 and waited per row: with ONE wave,
// ~120cy LDS latency exposed on every row. v5's 203us had the mirror
// failure (regalloc reused asm-load dests -> hazard waits).
// v8: per group, after the vmcnt gate, load all 16 f32x4 (8 rows) into
// NAMED registers (64 VGPRs, low pressure -> no reuse), sched_barrier(0)
// pins issue-before-compute, then 8 branch-free DPROWs from registers.
// Compiler emits counted lgkmcnt waits: only the first row pays ~120cy
// per group (~15cy/row amortized). Additional shaves:
//   - y==0 handled in a dedicated group-0 prologue (hot loop branch-free).
//   - x==y fold via per-group mask constants OR'd at store (saves 2/row).
// vmcnt schedule (16 loads + 2 stores per group, prologue stages 4 groups):
// W(48) at iter g leaves {S_{g-1}, L_{g+1..g+3}} -> L_g complete. Tails
// 32/16/0 re-derived identically. Dirs layout unchanged (k_bwd as-is).
// ---------------------------------------------------------------------------
#define WAIT_VM(N) do {                                                   \
    asm volatile("s_waitcnt vmcnt(" #N ")" ::: "memory");                 \
    __builtin_amdgcn_sched_barrier(0);                                    \
} while (0)

#define GLDS(GP, LP)                                                      \
    __builtin_amdgcn_global_load_lds(                                     \
        (__attribute__((address_space(1))) void*)(GP),                    \
        (__attribute__((address_space(3))) void*)(LP), 16, 0, 0)

// Stage group G (8 rows x 512 f = 16KB) into ring slot G&3.
// gsrc is per-lane (includes the swizzled lane*16 offset); LDS base is
// wave-uniform (HW adds lane*16). Swizzle P = L ^ (((L>>7)&1)<<4) realized
// as pre-swizzled global source + swizzled read offsets (verified R18).
#define STAGE(G) do {                                                     \
    const char* gb_ = gsrc + (size_t)(G) * 16384;                         \
    char* lb_ = ring + (((G) & 3) * 16384);                               \
    _Pragma("unroll")                                                     \
    for (int c_ = 0; c_ < 16; ++c_)                                       \
        GLDS(gb_ + c_ * 1024, lb_ + c_ * 1024);                           \
} while (0)

// Load all 8 rows (16 x f32x4) of slot SL into named registers.
#define LOADQ(SL)                                                         \
    const char* sp_ = (SL) + lbase;                                       \
    f32x4 q0l = *(const f32x4*)(sp_ + sw0);                               \
    f32x4 q0h = *(const f32x4*)(sp_ + sw1);                               \
    f32x4 q1l = *(const f32x4*)(sp_ + 2048 + sw0);                        \
    f32x4 q1h = *(const f32x4*)(sp_ + 2048 + sw1);                        \
    f32x4 q2l = *(const f32x4*)(sp_ + 4096 + sw0);                        \
    f32x4 q2h = *(const f32x4*)(sp_ + 4096 + sw1);                        \
    f32x4 q3l = *(const f32x4*)(sp_ + 6144 + sw0);                        \
    f32x4 q3h = *(const f32x4*)(sp_ + 6144 + sw1);                        \
    f32x4 q4l = *(const f32x4*)(sp_ + 8192 + sw0);                        \
    f32x4 q4h = *(const f32x4*)(sp_ + 8192 + sw1);                        \
    f32x4 q5l = *(const f32x4*)(sp_ + 10240 + sw0);                       \
    f32x4 q5h = *(const f32x4*)(sp_ + 10240 + sw1);                       \
    f32x4 q6l = *(const f32x4*)(sp_ + 12288 + sw0);                       \
    f32x4 q6h = *(const f32x4*)(sp_ + 12288 + sw1);                       \
    f32x4 q7l = *(const f32x4*)(sp_ + 14336 + sw0);                       \
    f32x4 q7h = *(const f32x4*)(sp_ + 14336 + sw1);                       \
    __builtin_amdgcn_sched_barrier(0);

// One DP row from registers (branch-free; y>0 semantics).
#define DPROW(QL, QH, R) do {                                                 \
    float s0_ = QL[0], s1_ = QL[1], s2_ = QL[2], s3_ = QL[3];                 \
    float s4_ = QH[0], s5_ = QH[1], s6_ = QH[2], s7_ = QH[3];                 \
    unsigned d_ = 0;                                                          \
    float pl_ = __int_as_float(__builtin_amdgcn_update_dpp(                   \
        0, __float_as_int(v[7]), 0x138, 0xF, 0xF, false));                    \
    if (lane == 0) pl_ = NEG_INF;                                             \
    float n0_ = s0_ + fmaxf(v[0], pl_);  if (pl_  > v[0]) d_ |= 1u;           \
    float n1_ = s1_ + fmaxf(v[1], v[0]); if (v[0] > v[1]) d_ |= 2u;           \
    float n2_ = s2_ + fmaxf(v[2], v[1]); if (v[1] > v[2]) d_ |= 4u;           \
    float n3_ = s3_ + fmaxf(v[3], v[2]); if (v[2] > v[3]) d_ |= 8u;           \
    float n4_ = s4_ + fmaxf(v[4], v[3]); if (v[3] > v[4]) d_ |= 16u;          \
    float n5_ = s5_ + fmaxf(v[5], v[4]); if (v[4] > v[5]) d_ |= 32u;          \
    float n6_ = s6_ + fmaxf(v[6], v[5]); if (v[5] > v[6]) d_ |= 64u;          \
    float n7_ = s7_ + fmaxf(v[7], v[6]); if (v[6] > v[7]) d_ |= 128u;         \
    v[0] = n0_; v[1] = n1_; v[2] = n2_; v[3] = n3_;                           \
    v[4] = n4_; v[5] = n5_; v[6] = n6_; v[7] = n7_;                           \
    acc |= d_ << (((R) & 3) * 8);                                             \
} while (0)

__global__ __launch_bounds__(64, 1) void k_fwd(const float* __restrict__ neg,
                                               const int* __restrict__ lens,
                                               uint32_t* __restrict__ dirs) {
    __shared__ __align__(16) char ring[4 * 16384];   // 64 KiB ring
    int b = blockIdx.x, lane = threadIdx.x;
    // global source pre-swizzle: lane fetches granule lane ^ ((lane>>3)&1)
    unsigned gsw = ((unsigned)lane * 16u) ^ ((((unsigned)lane >> 3) & 1u) << 4);
    const char* gsrc = (const char*)(neg + (size_t)b * TYY * TXX) + gsw;
    unsigned lbase = (unsigned)lane * 32u;
    unsigned sw0 = (((unsigned)lane >> 2) & 1u) << 4;   // swizzled lo offset
    unsigned sw1 = sw0 ^ 16u;                           // swizzled hi offset
    uint32_t* db32 = dirs + (size_t)b * (TYY / 4) * 64;
    int slen = lens[8 + b];
    int ng = (slen + 7) >> 3;    // 192..256 (slen >= 1536)

    float v[8];
#pragma unroll
    for (int j = 0; j < 8; ++j) v[j] = NEG_INF;
    unsigned acc = 0;

    STAGE(0); STAGE(1); STAGE(2); STAGE(3);   // 4-group lead (64 vmem)
    WAIT_VM(48);                              // slot 0 complete

    {   // ---- group 0 (row 0 special: only x==0 scored) ----
        LOADQ(ring);
        unsigned fm0 = (lane == 0) ? 0x08040201u : 0u;  // x==y fold, rows 0-3
        unsigned fm1 = (lane == 0) ? 0x80402010u : 0u;  // x==y fold, rows 4-7
        if (lane == 0) v[0] = q0l[0];
        // row 0 contributes no direction bits (acc stays 0 for r=0)
        DPROW(q1l, q1h, 1); DPROW(q2l, q2h, 2); DPROW(q3l, q3h, 3);
        uint32_t* dp_ = db32 + lane;
        dp_[0] = acc | fm0; acc = 0;
        DPROW(q4l, q4h, 4); DPROW(q5l, q5h, 5);
        DPROW(q6l, q6h, 6); DPROW(q7l, q7h, 7);
        dp_[64] = acc | fm1; acc = 0;
    }

#pragma unroll 1
    for (int g = 1; g < ng; ++g) {
        if (g + 3 < ng)      { STAGE(g + 3); WAIT_VM(48); }
        else if (g + 2 < ng) { WAIT_VM(32); }
        else if (g + 1 < ng) { WAIT_VM(16); }
        else                 { WAIT_VM(0);  }
        const char* sl = ring + ((g & 3) * 16384);
        LOADQ(sl);
        unsigned fm0 = (lane == g) ? 0x08040201u : 0u;
        unsigned fm1 = (lane == g) ? 0x80402010u : 0u;
        uint32_t* dp_ = db32 + ((unsigned)g << 7) + lane;
        DPROW(q0l, q0h, 0); DPROW(q1l, q1h, 1);
        DPROW(q2l, q2h, 2); DPROW(q3l, q3h, 3);
        dp_[0] = acc | fm0; acc = 0;
        DPROW(q4l, q4h, 4); DPROW(q5l, q5h, 5);
        DPROW(q6l, q6h, 6); DPROW(q7l, q7h, 7);
        dp_[64] = acc | fm1; acc = 0;
    }
}

// MAS backtrack: 32-row slabs; lane j holds a 64-bit window of row y0-j's
// bits; move = (idx!=0) & bit (x==y folded in fwd).
__global__ __launch_bounds__(64, 1) void k_bwd(const int* __restrict__ lens,
                                               const uint32_t* __restrict__ dirs,
                                               int* __restrict__ idx_map) {
    int b = blockIdx.x, lane = threadIdx.x;
    const uint32_t* db32 = dirs + (size_t)b * (TYY / 4) * 64;
    int tlen = lens[b], slen = lens[8 + b];

    int idx = tlen - 1;
    int y0 = slen - 1;
    while (y0 >= 0) {
        int nsteps = (y0 + 1 < 32) ? y0 + 1 : 32;
        int y = y0 - lane;
        int yy = (y < 0) ? 0 : y;
        int w0 = (idx >> 5) - 1;
        if (w0 < 0) w0 = 0;
        if (w0 > 14) w0 = 14;
        int qrow = (yy >> 2) * 64;
        int byteoff = (yy & 3) * 8;
        uint32_t lo = 0, hi = 0;
        if (lane < 32) {
#pragma unroll
            for (int k = 0; k < 4; ++k)
                lo |= ((db32[qrow + 4 * w0 + k] >> byteoff) & 0xffu) << (8 * k);
#pragma unroll
            for (int k = 0; k < 4; ++k)
                hi |= ((db32[qrow + 4 * w0 + 4 + k] >> byteoff) & 0xffu) << (8 * k);
        }
        int base = w0 << 5;
        int cap = 0;
#pragma unroll
        for (int j = 0; j < 32; ++j) {
            if (lane == j) cap = idx;
            uint32_t l = (uint32_t)__builtin_amdgcn_readlane((int)lo, j);
            uint32_t h = (uint32_t)__builtin_amdgcn_readlane((int)hi, j);
            int bp = idx - base;              // 0..63
            uint32_t word = (bp & 32) ? h : l;
            int bit = (int)((word >> (bp & 31)) & 1u);
            int move = (int)(idx != 0) & bit;
            idx -= move;
        }
        if (lane < nsteps) idx_map[b * TYY + (y0 - lane)] = cap;
        y0 -= 32;
    }
}

// Scatter path one-hots + duration histogram from idx_map.
__global__ void k_scatter(const int* __restrict__ lens, const int* __restrict__ idx_map,
                          float* __restrict__ out) {
    int i = blockIdx.x * blockDim.x + threadIdx.x;  // B*Ty threads
    int b = i >> 11, y = i & (TYY - 1);
    if (y < lens[8 + b]) {
        int x = idx_map[i];
        out[(size_t)i * TXX + x] = 1.0f;
        atomicAdd(&out[O4 + b * TXX + x], 1.0f);
    }
}

// Gather m_p/logs_p onto spec frames via idx_map; fused KL partial sums.
__global__ __launch_bounds__(256) void k_gather(const float* __restrict__ z_p,
                                                const float* __restrict__ m_p,
                                                const float* __restrict__ logs_p,
                                                const float* __restrict__ logs_q,
                                                const int* __restrict__ lens,
                                                const int* __restrict__ idx_map,
                                                float* __restrict__ out,
                                                float* __restrict__ partials) {
    const int S = BB * CC * TYY / 4;
    int base = blockIdx.x * 256 + threadIdx.x;
    float klsum = 0.f;
#pragma unroll
    for (int r = 0; r < 4; ++r) {
        int i = base + r * S;
        int t = i & (TYY - 1);
        int bc = i >> 11;
        int b = bc / CC;
        float ma = 0.f, la = 0.f;
        if (t < lens[8 + b]) {
            int x = idx_map[b * TYY + t];
            size_t off = (size_t)bc * TXX + x;
            ma = m_p[off];
            la = logs_p[off];
            float zv = z_p[i], lq = logs_q[i];
            float dz = zv - ma;
            klsum += la - lq - 0.5f + 0.5f * dz * dz * expf(-2.0f * la);
        }
        out[O1 + i] = ma;
        out[O2 + i] = la;
    }
    for (int o = 32; o > 0; o >>= 1) klsum += __shfl_down(klsum, o);
    __shared__ float red[4];
    if ((threadIdx.x & 63) == 0) red[threadIdx.x >> 6] = klsum;
    __syncthreads();
    if (threadIdx.x == 0) partials[blockIdx.x] = red[0] + red[1] + red[2] + red[3];
}

__global__ void k_final(const float* __restrict__ partials, const int* __restrict__ lens,
                        float* __restrict__ out) {
    float s = 0.f;
    for (int i = threadIdx.x; i < 3072; i += 256) s += partials[i];
    for (int o = 32; o > 0; o >>= 1) s += __shfl_down(s, o);
    __shared__ float red[4];
    if ((threadIdx.x & 63) == 0) red[threadIdx.x >> 6] = s;
    __syncthreads();
    if (threadIdx.x == 0) {
        float tot = 0.f;
        for (int b = 0; b < 8; ++b) tot += (float)lens[8 + b];
        out[O3] = (red[0] + red[1] + red[2] + red[3]) / tot;
    }
}

extern "C" void kernel_launch(void* const* d_in, const int* in_sizes, int n_in,
                              void* d_out, int out_size, void* d_ws, size_t ws_size,
                              hipStream_t stream) {
    const float* z_p    = (const float*)d_in[0];
    const float* m_p    = (const float*)d_in[1];
    const float* logs_p = (const float*)d_in[2];
    const float* logs_q = (const float*)d_in[3];
    const float* tmask  = (const float*)d_in[4];
    const float* smask  = (const float*)d_in[5];
    float* out = (float*)d_out;
    char* ws = (char*)d_ws;

    float*    neg      = (float*)(ws + WS_NEG);
    float*    sarr     = (float*)(ws + WS_S);
    float*    msr      = (float*)(ws + WS_MSR);
    float*    bias     = (float*)(ws + WS_BIAS);
    uint32_t* dirs     = (uint32_t*)(ws + WS_DIRS);
    int*      idx_map  = (int*)(ws + WS_IDX);
    int*      lens     = (int*)(ws + WS_LENS);
    float*    partials = (float*)(ws + WS_PART);

    hipLaunchKernelGGL(k_zero,    dim3(2048),      dim3(256), 0, stream, out);
    hipLaunchKernelGGL(k_prep,    dim3(3072),      dim3(256), 0, stream, logs_p, m_p, sarr, msr);
    hipLaunchKernelGGL(k_bias,    dim3(16),        dim3(256), 0, stream, logs_p, m_p, msr, bias);
    hipLaunchKernelGGL(k_len,     dim3(8),         dim3(256), 0, stream, tmask, smask, lens);
    hipLaunchKernelGGL(k_gemm,    dim3(8, 32, 8),  dim3(256), 0, stream, z_p, msr, sarr, bias, lens, neg);
    hipLaunchKernelGGL(k_fwd,     dim3(8),         dim3(64),  0, stream, neg, lens, dirs);
    hipLaunchKernelGGL(k_bwd,     dim3(8),         dim3(64),  0, stream, lens, dirs, idx_map);
    hipLaunchKernelGGL(k_scatter, dim3(64),        dim3(256), 0, stream, lens, idx_map, out);
    hipLaunchKernelGGL(k_gather,  dim3(3072),      dim3(256), 0, stream, z_p, m_p, logs_p, logs_q,
                       lens, idx_map, out, partials);
    hipLaunchKernelGGL(k_final,   dim3(1),         dim3(256), 0, stream, partials, lens, out);
}